// Round 10
// baseline (3593.550 us; speedup 1.0000x reference)
//
#include <hip/hip_runtime.h>

// ---------------------------------------------------------------------------
// SparseEncoderResUNet on MI355X — round 10: conv occupancy doubling.
// r9 diagnosis: MFMA convs latency-bound at 16 waves/CU (grid-limited, 36%
// occupancy, MfmaUtil 15%). Fix: split co across 2x blocks (NCT 2->1, grid.y
// x2) for all five MFMA convs -> 32 waves/CU requested. A-fragment aggregate
// traffic unchanged; B traffic (small) doubles. Accumulation order per output
// unchanged -> bit-identical (absmax 0.0). All else identical to r9.
// ---------------------------------------------------------------------------

enum { EPI_MASK = 1, EPI_LEAKY = 2, EPI_RESID = 4 };
#define ROWCAP 32768

typedef short  bf16x8 __attribute__((ext_vector_type(8)));
typedef float  f32x4  __attribute__((ext_vector_type(4)));
typedef ushort us4    __attribute__((ext_vector_type(4)));

__device__ __forceinline__ float leaky(float v) { return v >= 0.f ? v : 0.2f * v; }
__device__ __forceinline__ ushort f2bf(float f) {
    unsigned u = __float_as_uint(f);
    return (ushort)((u + 0x7FFFu + ((u >> 16) & 1u)) >> 16);
}
__device__ __forceinline__ float bf2f(ushort h) {
    return __uint_as_float((unsigned)h << 16);
}
// channel c -> offset within a voxel's CI*2 block (interleaved hi/lo by 8)
__device__ __forceinline__ int choff(int c) {
    return (c >> 5) * 64 + ((c >> 3) & 3) * 16 + (c & 7);
}

// ---------------- weight transpose: w[co][cik] -> wT[cik][co] ----------------
__global__ __launch_bounds__(256) void transpose_w_kernel(
    const float* __restrict__ w, float* __restrict__ wT, int CO, int CIK)
{
    int i = blockIdx.x * 256 + threadIdx.x;
    if (i >= CO * CIK) return;
    int co = i / CIK, r = i - co * CIK;
    wT[(size_t)r * CO + co] = w[i];
}

// interleaved-by-4 layout for stage1b
__global__ __launch_bounds__(256) void transpose_w4_kernel(
    const float* __restrict__ w, float* __restrict__ w4, int CO, int CIK)
{
    int i = blockIdx.x * 256 + threadIdx.x;
    if (i >= CO * CIK) return;
    int co = i / CIK, r = i - co * CIK;
    w4[(((size_t)(r >> 2) * CO) + co) * 4 + (r & 3)] = w[i];
}

// ---------------- pack weights into MFMA A-frag layout, hi/lo interleaved ----
__global__ __launch_bounds__(256) void pack_w_kernel(
    const float* __restrict__ w, ushort* __restrict__ A, int CI, int CO)
{
    int i = blockIdx.x * 256 + threadIdx.x;
    if (i >= 27 * CI * CO * 2) return;
    int j = i & 7, hilo = (i >> 3) & 1, L = (i >> 4) & 63, rest = i >> 10;
    int NMT = CO >> 4, NCI = CI >> 5;
    int mt = rest % NMT; rest /= NMT;
    int ct = rest % NCI;
    int tap = rest / NCI;
    int co = mt * 16 + (L & 15);
    int ci = ct * 32 + (L >> 4) * 8 + j;
    float v = w[((size_t)co * CI + ci) * 27 + tap];
    ushort h = f2bf(v);
    A[i] = hilo ? f2bf(v - bf2f(h)) : h;
}

// ---------------- maxpool k3 s2 p1 (down_mask) ----------------
template<int DIN, int DOUT>
__global__ __launch_bounds__(256) void maxpool_kernel(
    const float* __restrict__ in, float* __restrict__ out)
{
    int i = blockIdx.x * 256 + threadIdx.x;
    constexpr int D3O = DOUT * DOUT * DOUT;
    if (i >= 2 * D3O) return;
    int b = i / D3O;
    int v = i - b * D3O;
    int z = v / (DOUT * DOUT), y = (v / DOUT) % DOUT, x = v % DOUT;
    float mx = 0.f;
    #pragma unroll
    for (int dz = 0; dz < 3; ++dz)
        #pragma unroll
        for (int dy = 0; dy < 3; ++dy)
            #pragma unroll
            for (int dx = 0; dx < 3; ++dx) {
                int zi = 2 * z - 1 + dz, yi = 2 * y - 1 + dy, xi = 2 * x - 1 + dx;
                if ((unsigned)zi < (unsigned)DIN && (unsigned)yi < (unsigned)DIN &&
                    (unsigned)xi < (unsigned)DIN)
                    mx = fmaxf(mx, in[(size_t)b * DIN * DIN * DIN + (zi * DIN + yi) * DIN + xi]);
            }
    out[i] = mx;
}

// ---------------- active-voxel list + dense index map ----------------
__global__ __launch_bounds__(256) void build_list_kernel(
    const float* __restrict__ m, int* __restrict__ list, int* __restrict__ idxmap,
    int* __restrict__ count)
{
    int i = blockIdx.x * 256 + threadIdx.x;
    if (i >= 2 * 262144) return;
    if (m[i] > 0.5f) {
        int k = atomicAdd(count, 1);
        if (k < ROWCAP) {
            list[k] = i;
            idxmap[i] = k;
        }
    }
}

// ---------------- stage1 conv-a (3->64, gathered) -> t1c[row][64] ----------------
__global__ __launch_bounds__(64) void stage1a_kernel(
    const float* __restrict__ x, const float* __restrict__ waT,
    const int* __restrict__ list, const int* __restrict__ count,
    float* __restrict__ t1c)
{
    __shared__ float smem[81];
    int n = min(*count, ROWCAP);
    for (int i = blockIdx.x; i < n; i += gridDim.x) {
        int lin = list[i];
        int b = lin >> 18;
        int v = lin & 262143;
        int z = v >> 12, y = (v >> 6) & 63, xx = v & 63;
        for (int j = threadIdx.x; j < 81; j += 64) {
            int ci = j / 27, t = j - ci * 27;
            int zz = z + t / 9 - 1, yy = y + (t / 3) % 3 - 1, xc = xx + t % 3 - 1;
            float val = 0.f;
            if ((unsigned)zz < 64u && (unsigned)yy < 64u && (unsigned)xc < 64u)
                val = x[(size_t)(b * 3 + ci) * 262144 + (zz << 12) + (yy << 6) + xc];
            smem[j] = val;
        }
        __syncthreads();
        float acc = 0.f;
        #pragma unroll 9
        for (int j = 0; j < 81; ++j)
            acc = fmaf(smem[j], waT[j * 64 + threadIdx.x], acc);
        t1c[(size_t)i * 64 + threadIdx.x] = leaky(acc);
        __syncthreads();
    }
}

// ---------------- stage1 conv-b (64->64, gathered) + 1x1 identity ----------------
__global__ __launch_bounds__(64) void stage1b_kernel(
    const float* __restrict__ t1c, const float* __restrict__ x,
    const float* __restrict__ wb4, const float* __restrict__ wdT,
    const int* __restrict__ list, const int* __restrict__ idxmap,
    const int* __restrict__ count,
    float* __restrict__ x1c)
{
    __shared__ float sw[4 * 1728];
    int n = min(*count, ROWCAP);
    int nq = (n + 3) >> 2;
    for (int q = blockIdx.x; q < nq; q += gridDim.x) {
        for (int vv = 0; vv < 4; ++vv) {
            int i = q * 4 + vv;
            int lin = (i < n) ? list[i] : list[0];
            int b = lin >> 18;
            int v = lin & 262143;
            int z = v >> 12, y = (v >> 6) & 63, xx = v & 63;
            const int* im = idxmap + b * 262144;
            #pragma unroll
            for (int t = 0; t < 27; ++t) {
                int zz = z + t / 9 - 1, yy = y + (t / 3) % 3 - 1, xc = xx + t % 3 - 1;
                float val = 0.f;
                if ((unsigned)zz < 64u && (unsigned)yy < 64u && (unsigned)xc < 64u) {
                    int r = im[(zz << 12) + (yy << 6) + xc];
                    if (r >= 0)
                        val = t1c[(size_t)r * 64 + threadIdx.x];
                }
                sw[vv * 1728 + threadIdx.x * 27 + t] = val;
            }
        }
        __syncthreads();
        float acc[4] = {0.f, 0.f, 0.f, 0.f};
        const float* wp = wb4 + threadIdx.x * 4;
        for (int j4 = 0; j4 < 432; ++j4) {
            float4 w = *(const float4*)(wp + (size_t)j4 * 256);
            #pragma unroll
            for (int vv = 0; vv < 4; ++vv) {
                float4 s = *(const float4*)(&sw[vv * 1728 + j4 * 4]);
                acc[vv] = fmaf(s.x, w.x, acc[vv]);
                acc[vv] = fmaf(s.y, w.y, acc[vv]);
                acc[vv] = fmaf(s.z, w.z, acc[vv]);
                acc[vv] = fmaf(s.w, w.w, acc[vv]);
            }
        }
        #pragma unroll
        for (int vv = 0; vv < 4; ++vv) {
            int i = q * 4 + vv;
            if (i < n) {
                int lin = list[i];
                int b = lin >> 18;
                int v = lin & 262143;
                float id = 0.f;
                #pragma unroll
                for (int ci = 0; ci < 3; ++ci)
                    id = fmaf(x[(size_t)(b * 3 + ci) * 262144 + v], wdT[ci * 64 + threadIdx.x], id);
                x1c[(size_t)i * 64 + threadIdx.x] = leaky(acc[vv] + id);
            }
        }
        __syncthreads();
    }
}

// ---------------- wd1 v2: lanes = channels, wave-uniform tap skip -------------
__global__ __launch_bounds__(128) void wd1_kernel(
    const float* __restrict__ x1c, const int* __restrict__ idxmap,
    const float* __restrict__ wT,   // [ci*27+tap][128]
    ushort* __restrict__ outp)
{
    __shared__ int   srr[27];
    __shared__ float sx[27][64];
    const int tid = threadIdx.x;
    const int v = blockIdx.x;           // 0..32767
    const int b = blockIdx.y;
    const int zo = v >> 10, yo = (v >> 5) & 31, xo = v & 31;
    const int* im = idxmap + b * 262144;

    if (tid < 27) {
        int kz = tid / 9, ky = (tid / 3) % 3, kx = tid % 3;
        int zi = 2 * zo - 1 + kz, yi = 2 * yo - 1 + ky, xi = 2 * xo - 1 + kx;
        int r = -1;
        if ((unsigned)zi < 64u && (unsigned)yi < 64u && (unsigned)xi < 64u)
            r = im[(zi << 12) + (yi << 6) + xi];
        srr[tid] = r;
    }
    __syncthreads();
    #pragma unroll 1
    for (int t = 0; t < 27; ++t) {
        int r = srr[t];
        if (r >= 0 && tid < 64)
            sx[t][tid] = x1c[(size_t)r * 64 + tid];
    }
    __syncthreads();

    float acc = 0.f;
    #pragma unroll 1
    for (int t = 0; t < 27; ++t) {
        if (srr[t] < 0) continue;
        const float* wp = wT + (size_t)t * 128 + tid;
        const float* xr = sx[t];
        #pragma unroll 8
        for (int ci = 0; ci < 64; ++ci)
            acc = fmaf(xr[ci], wp[(size_t)ci * 27 * 128], acc);
    }
    float val = leaky(acc);
    ushort hb = f2bf(val);
    ushort lb = f2bf(val - bf2f(hb));
    size_t vb = ((((size_t)b * 32 + zo) * 32 + yo) * 33 + xo) * 256 + 256;
    int off = choff(tid);
    outp[vb + off] = hb;
    outp[vb + off + 8] = lb;
}

// ---------------- MFMA implicit-GEMM conv v3 (3-product, interleaved) --------
template<int CI, int CO, int DI, int DO, int S, int RY, int NX, int NCT, int EPI>
__global__ __launch_bounds__(256) void mfma_conv3_kernel(
    const ushort* __restrict__ inp, const ushort* __restrict__ A,
    const float* __restrict__ mask, const ushort* __restrict__ resid,
    ushort* __restrict__ outp)
{
    constexpr int NCI = CI / 32;
    constexpr int NMT = CO / 16;
    constexpr int CV = CI * 2;
    constexpr int CVO = CO * 2;
    constexpr int YG = DO / RY;
    const int rg = blockIdx.x;
    const int y0 = (rg % YG) * RY;
    const int z = (rg / YG) % DO;
    const int b = rg / (YG * DO);
    const int wave = threadIdx.x >> 6;
    const int lane = threadIdx.x & 63;
    const int n_l = lane & 15;
    const int q = lane >> 4;
    const int mt0 = (blockIdx.y * 4 + wave) * NCT;

    f32x4 acc[NCT][RY][NX];
    #pragma unroll
    for (int a = 0; a < NCT; ++a)
        #pragma unroll
        for (int r = 0; r < RY; ++r)
            #pragma unroll
            for (int c = 0; c < NX; ++c)
                acc[a][r][c] = (f32x4){0.f, 0.f, 0.f, 0.f};

    const bf16x8 zero8 = {0, 0, 0, 0, 0, 0, 0, 0};

    for (int ct = 0; ct < NCI; ++ct) {
        #pragma unroll
        for (int dz = 0; dz < 3; ++dz) {
            int zp = z * S + dz - 1;
            if ((unsigned)zp >= (unsigned)DI) continue;
            #pragma unroll
            for (int dy = 0; dy < 3; ++dy) {
                size_t rowb[RY];
                bool vy[RY];
                #pragma unroll
                for (int ry = 0; ry < RY; ++ry) {
                    int yp = (y0 + ry) * S + dy - 1;
                    vy[ry] = (unsigned)yp < (unsigned)DI;
                    rowb[ry] = ((((size_t)b * DI + zp) * DI + (vy[ry] ? yp : 0)) * (DI + 1)) * CV + CV;
                }
                #pragma unroll
                for (int dx = 0; dx < 3; ++dx) {
                    const int tap = dz * 9 + dy * 3 + dx;
                    bf16x8 bh[RY][NX], bl[RY][NX];
                    #pragma unroll
                    for (int ry = 0; ry < RY; ++ry)
                        #pragma unroll
                        for (int nx = 0; nx < NX; ++nx) {
                            if (vy[ry]) {
                                int xp = (nx * 16 + n_l) * S + dx - 1;
                                size_t ba = rowb[ry] + (size_t)xp * CV + ct * 64 + q * 16;
                                bh[ry][nx] = *(const bf16x8*)(inp + ba);
                                bl[ry][nx] = *(const bf16x8*)(inp + ba + 8);
                            } else {
                                bh[ry][nx] = zero8;
                                bl[ry][nx] = zero8;
                            }
                        }
                    #pragma unroll
                    for (int mt = 0; mt < NCT; ++mt) {
                        size_t aa = ((size_t)(tap * NCI + ct) * NMT + (mt0 + mt)) * 1024 + lane * 16;
                        bf16x8 ahf = *(const bf16x8*)(A + aa);
                        bf16x8 alf = *(const bf16x8*)(A + aa + 8);
                        #pragma unroll
                        for (int ry = 0; ry < RY; ++ry)
                            #pragma unroll
                            for (int nx = 0; nx < NX; ++nx) {
                                acc[mt][ry][nx] = __builtin_amdgcn_mfma_f32_16x16x32_bf16(ahf, bh[ry][nx], acc[mt][ry][nx], 0, 0, 0);
                                acc[mt][ry][nx] = __builtin_amdgcn_mfma_f32_16x16x32_bf16(ahf, bl[ry][nx], acc[mt][ry][nx], 0, 0, 0);
                                acc[mt][ry][nx] = __builtin_amdgcn_mfma_f32_16x16x32_bf16(alf, bh[ry][nx], acc[mt][ry][nx], 0, 0, 0);
                            }
                    }
                }
            }
        }
    }

    #pragma unroll
    for (int ry = 0; ry < RY; ++ry) {
        int yo = y0 + ry;
        #pragma unroll
        for (int nx = 0; nx < NX; ++nx) {
            int xo = nx * 16 + n_l;
            size_t vb = ((((size_t)b * DO + z) * DO + yo) * (DO + 1)) * CVO + CVO + (size_t)xo * CVO;
            float mval = 1.f;
            if (EPI & EPI_MASK) mval = mask[(((size_t)b * DO + z) * DO + yo) * DO + xo];
            #pragma unroll
            for (int mt = 0; mt < NCT; ++mt) {
                int c0 = (mt0 + mt) * 16 + q * 4;
                size_t oa = vb + choff(c0);
                float rs[4] = {0.f, 0.f, 0.f, 0.f};
                if (EPI & EPI_RESID) {
                    us4 rh4 = *(const us4*)(resid + oa);
                    us4 rl4 = *(const us4*)(resid + oa + 8);
                    #pragma unroll
                    for (int r = 0; r < 4; ++r) rs[r] = bf2f(rh4[r]) + bf2f(rl4[r]);
                }
                us4 oh, ol;
                #pragma unroll
                for (int r = 0; r < 4; ++r) {
                    float v = acc[mt][ry][nx][r];
                    if (EPI & EPI_MASK) v *= mval;
                    if (EPI & EPI_RESID) v += rs[r];
                    if (EPI & EPI_LEAKY) v = leaky(v);
                    ushort hb = f2bf(v);
                    oh[r] = hb;
                    ol[r] = f2bf(v - bf2f(hb));
                }
                *(us4*)(outp + oa) = oh;
                *(us4*)(outp + oa + 8) = ol;
            }
        }
    }
}

// ---------------- wd3 via MFMA (3-product, interleaved) -> x4 fp32 ------------
__global__ __launch_bounds__(256) void wd3_mfma_kernel(
    const ushort* __restrict__ x3, const ushort* __restrict__ A,
    float* __restrict__ x4)
{
    constexpr int NCI = 8;   // 256/32
    constexpr int NMT = 8;   // 128/16
    const int blk = blockIdx.x;
    const int yg = blk & 3;
    const int z = (blk >> 2) & 7;
    const int b = blk >> 5;
    const int wave = threadIdx.x >> 6;
    const int lane = threadIdx.x & 63;
    const int n_l = lane & 15;
    const int q = lane >> 4;
    const int y = yg * 2 + (n_l >> 3);
    const int x = n_l & 7;
    const int mt0 = wave * 2;

    f32x4 acc[2];
    acc[0] = (f32x4){0.f, 0.f, 0.f, 0.f};
    acc[1] = (f32x4){0.f, 0.f, 0.f, 0.f};
    const bf16x8 zero8 = {0, 0, 0, 0, 0, 0, 0, 0};

    for (int ct = 0; ct < NCI; ++ct) {
        #pragma unroll
        for (int dz = 0; dz < 3; ++dz) {
            int zp = 2 * z + dz - 1;
            if ((unsigned)zp >= 16u) continue;
            #pragma unroll
            for (int dy = 0; dy < 3; ++dy) {
                int yp = 2 * y + dy - 1;
                bool vy = (unsigned)yp < 16u;
                int ypc = vy ? yp : 0;
                #pragma unroll
                for (int dx = 0; dx < 3; ++dx) {
                    int xp = 2 * x + dx - 1;
                    int tap = dz * 9 + dy * 3 + dx;
                    size_t ba = ((((size_t)b * 16 + zp) * 16 + ypc) * 17 + 1 + xp) * 512
                              + ct * 64 + q * 16;
                    bf16x8 bh = vy ? *(const bf16x8*)(x3 + ba) : zero8;
                    bf16x8 bl = vy ? *(const bf16x8*)(x3 + ba + 8) : zero8;
                    #pragma unroll
                    for (int mt = 0; mt < 2; ++mt) {
                        size_t aa = ((size_t)(tap * NCI + ct) * NMT + (mt0 + mt)) * 1024 + lane * 16;
                        bf16x8 ahf = *(const bf16x8*)(A + aa);
                        bf16x8 alf = *(const bf16x8*)(A + aa + 8);
                        acc[mt] = __builtin_amdgcn_mfma_f32_16x16x32_bf16(ahf, bh, acc[mt], 0, 0, 0);
                        acc[mt] = __builtin_amdgcn_mfma_f32_16x16x32_bf16(ahf, bl, acc[mt], 0, 0, 0);
                        acc[mt] = __builtin_amdgcn_mfma_f32_16x16x32_bf16(alf, bh, acc[mt], 0, 0, 0);
                    }
                }
            }
        }
    }
    #pragma unroll
    for (int mt = 0; mt < 2; ++mt)
        #pragma unroll
        for (int r = 0; r < 4; ++r) {
            int co = (mt0 + mt) * 16 + q * 4 + r;
            x4[((size_t)(b * 128 + co)) * 512 + z * 64 + y * 8 + x] = leaky(acc[mt][r]);
        }
}

// ---------------- final: mean/max pool over 8^3 -------------------------------
__global__ __launch_bounds__(64) void reduce_kernel(
    const float* __restrict__ x4, float* __restrict__ out)
{
    int bc = blockIdx.x;
    int b = bc >> 7, c = bc & 127;
    const float* p = x4 + (size_t)(b * 128 + c) * 512;
    float s = 0.f, mx = -3.4e38f;
    for (int i = threadIdx.x; i < 512; i += 64) {
        float v = p[i];
        s += v;
        mx = fmaxf(mx, v);
    }
    #pragma unroll
    for (int o = 32; o > 0; o >>= 1) {
        s += __shfl_down(s, o);
        mx = fmaxf(mx, __shfl_down(mx, o));
    }
    if (threadIdx.x == 0) {
        out[b * 256 + c] = s * (1.f / 512.f);
        out[b * 256 + 128 + c] = mx;
    }
}

__global__ __launch_bounds__(256) void zero_out_kernel(float* __restrict__ out, int n)
{
    int i = blockIdx.x * 256 + threadIdx.x;
    if (i < n) out[i] = 0.f;
}

// ---------------------------------------------------------------------------
extern "C" void kernel_launch(void* const* d_in, const int* in_sizes, int n_in,
                              void* d_out, int out_size, void* d_ws, size_t ws_size,
                              hipStream_t stream)
{
    (void)in_sizes; (void)n_in;
    const float* x    = (const float*)d_in[0];
    const float* mask = (const float*)d_in[1];
    const float* w1a  = (const float*)d_in[2];
    const float* w1b  = (const float*)d_in[3];
    const float* w1d  = (const float*)d_in[4];
    const float* wd1  = (const float*)d_in[5];
    const float* w2a  = (const float*)d_in[6];
    const float* w2b  = (const float*)d_in[7];
    const float* wd2  = (const float*)d_in[8];
    const float* w3a  = (const float*)d_in[9];
    const float* w3b  = (const float*)d_in[10];
    const float* wd3  = (const float*)d_in[11];
    float* out = (float*)d_out;
    char* ws = (char*)d_ws;

    const size_t RSZ = 34603520;      // stage-2 tensor region (interleaved)
    const size_t SZ3 = 8913920;       // stage-3 tensor bytes
    char* R1 = ws;
    char* R2 = ws + RSZ;
    char* R3 = ws + 2 * RSZ;
    size_t off = 3 * RSZ;
    auto alloc = [&](size_t bytes) { char* p = ws + off; off = (off + bytes + 255) & ~255ull; return p; };
    ushort* pk2a = (ushort*)alloc(1769472);
    ushort* pk2b = (ushort*)alloc(1769472);
    ushort* pkd2 = (ushort*)alloc(3538944);
    ushort* pk3a = (ushort*)alloc(7077888);
    ushort* pk3b = (ushort*)alloc(7077888);
    float*  wd1T = (float*)alloc(884736);
    float*  waT  = (float*)alloc(20736);
    float*  wb4  = (float*)alloc(442368);
    float*  wdTt = (float*)alloc(768);
    float*  m2   = (float*)alloc(262144);
    float*  m3   = (float*)alloc(32768);
    int*    cnt  = (int*)alloc(256);
    const size_t NEED = off;

    if (ws_size < NEED) {
        zero_out_kernel<<<dim3((out_size + 255) / 256), 256, 0, stream>>>(out, out_size);
        return;
    }

    // stage-1 scratch aliased into R2 (dead before t2 is written)
    float* t1c  = (float*)R2;
    float* x1c  = (float*)(R2 + 8388608);
    int*   idx  = (int*)(R2 + 16777216);
    int*   list = (int*)(R2 + 18874368);
    // late-phase aliases
    ushort* pkd3 = (ushort*)R1;       // xin3 dead after conv3b
    float*  x4   = (float*)R2;        // t3 dead after conv3b

    ushort* xin2 = (ushort*)R1;
    ushort* t2   = (ushort*)R2;
    ushort* x2   = (ushort*)R3;
    ushort* xin3 = (ushort*)R1;
    ushort* t3   = (ushort*)R2;
    ushort* x3   = (ushort*)R3;

    hipMemsetAsync(cnt, 0, 4, stream);
    hipMemsetAsync(idx, 0xFF, 2097152, stream);
    hipMemsetAsync(R1, 0, RSZ, stream);           // xin2 pads

    auto tg = [](int n) { return dim3((n + 255) / 256); };
    pack_w_kernel<<<tg(27 * 128 * 128 * 2), 256, 0, stream>>>(w2a, pk2a, 128, 128);
    pack_w_kernel<<<tg(27 * 128 * 128 * 2), 256, 0, stream>>>(w2b, pk2b, 128, 128);
    pack_w_kernel<<<tg(27 * 128 * 256 * 2), 256, 0, stream>>>(wd2, pkd2, 128, 256);
    pack_w_kernel<<<tg(27 * 256 * 256 * 2), 256, 0, stream>>>(w3a, pk3a, 256, 256);
    pack_w_kernel<<<tg(27 * 256 * 256 * 2), 256, 0, stream>>>(w3b, pk3b, 256, 256);
    transpose_w_kernel <<<tg(128 * 1728), 256, 0, stream>>>(wd1, wd1T, 128, 1728);
    transpose_w_kernel <<<tg(64 * 81),    256, 0, stream>>>(w1a, waT,  64, 81);
    transpose_w4_kernel<<<tg(64 * 1728),  256, 0, stream>>>(w1b, wb4,  64, 1728);
    transpose_w_kernel <<<tg(64 * 3),     256, 0, stream>>>(w1d, wdTt, 64, 3);

    maxpool_kernel<64, 32><<<dim3(2 * 32768 / 256), 256, 0, stream>>>(mask, m2);
    maxpool_kernel<32, 16><<<dim3(2 * 4096 / 256),  256, 0, stream>>>(m2, m3);
    build_list_kernel<<<dim3(2 * 262144 / 256), 256, 0, stream>>>(mask, list, idx, cnt);

    // stage 1 (sparse, fp32)
    stage1a_kernel<<<dim3(2048), 64, 0, stream>>>(x, waT, list, cnt, t1c);
    stage1b_kernel<<<dim3(2048), 64, 0, stream>>>(t1c, x, wb4, wdTt, list, idx, cnt, x1c);
    wd1_kernel<<<dim3(32768, 2), 128, 0, stream>>>(x1c, idx, wd1T, xin2);

    // stage-1 scratch dead; clear R2/R3 (t2/x2 pads)
    hipMemsetAsync(R2, 0, RSZ, stream);
    hipMemsetAsync(R3, 0, RSZ, stream);

    // stage2 res block: co split across grid.y (NCT=1) -> 2048 blocks, 32 waves/CU
    mfma_conv3_kernel<128, 128, 32, 32, 1, 2, 2, 1, EPI_MASK | EPI_LEAKY>
        <<<dim3(1024, 2), 256, 0, stream>>>(xin2, pk2a, m2, nullptr, t2);
    mfma_conv3_kernel<128, 128, 32, 32, 1, 2, 2, 1, EPI_MASK | EPI_RESID | EPI_LEAKY>
        <<<dim3(1024, 2), 256, 0, stream>>>(t2, pk2b, m2, xin2, x2);

    // xin2 dead -> clear xin3 area
    hipMemsetAsync(R1, 0, SZ3, stream);
    mfma_conv3_kernel<128, 256, 32, 16, 2, 2, 1, 1, EPI_LEAKY>
        <<<dim3(256, 4), 256, 0, stream>>>(x2, pkd2, nullptr, nullptr, xin3);

    hipMemsetAsync(R2, 0, SZ3, stream);
    mfma_conv3_kernel<256, 256, 16, 16, 1, 2, 1, 1, EPI_MASK | EPI_LEAKY>
        <<<dim3(256, 4), 256, 0, stream>>>(xin3, pk3a, m3, nullptr, t3);

    hipMemsetAsync(R3, 0, SZ3, stream);
    mfma_conv3_kernel<256, 256, 16, 16, 1, 2, 1, 1, EPI_MASK | EPI_RESID | EPI_LEAKY>
        <<<dim3(256, 4), 256, 0, stream>>>(t3, pk3b, m3, xin3, x3);

    // xin3 (R1) and t3 (R2) dead: pack wd3 -> R1, MFMA wd3 -> x4 (R2)
    pack_w_kernel<<<tg(27 * 256 * 128 * 2), 256, 0, stream>>>(wd3, pkd3, 256, 128);
    wd3_mfma_kernel<<<dim3(64), 256, 0, stream>>>(x3, pkd3, x4);

    reduce_kernel<<<dim3(256), 64, 0, stream>>>(x4, out);
}

// Round 11
// 2322.295 us; speedup vs baseline: 1.5474x; 1.5474x over previous
//
#include <hip/hip_runtime.h>

// ---------------------------------------------------------------------------
// SparseEncoderResUNet on MI355X — round 11: revert r10 + product-major MFMA.
// r10 REGRESSED (2337->3594): thinner waves (NCT=1) halved per-wave MFMA
// density; occupancy barely moved. Conclusion: convs are issue-efficiency
// bound, not wave-count bound. This round: exact r9 config, but the 3
// split-products are issued product-major across all accumulators so
// consecutive MFMAs never target the same acc (same-acc reuse distance
// 1 -> 8 instrs, covering MFMA->MFMA dependency latency). Per-acc product
// order unchanged (hh,hl,lh) -> bit-identical (absmax 0.0).
// ---------------------------------------------------------------------------

enum { EPI_MASK = 1, EPI_LEAKY = 2, EPI_RESID = 4 };
#define ROWCAP 32768

typedef short  bf16x8 __attribute__((ext_vector_type(8)));
typedef float  f32x4  __attribute__((ext_vector_type(4)));
typedef ushort us4    __attribute__((ext_vector_type(4)));

__device__ __forceinline__ float leaky(float v) { return v >= 0.f ? v : 0.2f * v; }
__device__ __forceinline__ ushort f2bf(float f) {
    unsigned u = __float_as_uint(f);
    return (ushort)((u + 0x7FFFu + ((u >> 16) & 1u)) >> 16);
}
__device__ __forceinline__ float bf2f(ushort h) {
    return __uint_as_float((unsigned)h << 16);
}
// channel c -> offset within a voxel's CI*2 block (interleaved hi/lo by 8)
__device__ __forceinline__ int choff(int c) {
    return (c >> 5) * 64 + ((c >> 3) & 3) * 16 + (c & 7);
}

// ---------------- weight transpose: w[co][cik] -> wT[cik][co] ----------------
__global__ __launch_bounds__(256) void transpose_w_kernel(
    const float* __restrict__ w, float* __restrict__ wT, int CO, int CIK)
{
    int i = blockIdx.x * 256 + threadIdx.x;
    if (i >= CO * CIK) return;
    int co = i / CIK, r = i - co * CIK;
    wT[(size_t)r * CO + co] = w[i];
}

// interleaved-by-4 layout for stage1b
__global__ __launch_bounds__(256) void transpose_w4_kernel(
    const float* __restrict__ w, float* __restrict__ w4, int CO, int CIK)
{
    int i = blockIdx.x * 256 + threadIdx.x;
    if (i >= CO * CIK) return;
    int co = i / CIK, r = i - co * CIK;
    w4[(((size_t)(r >> 2) * CO) + co) * 4 + (r & 3)] = w[i];
}

// ---------------- pack weights into MFMA A-frag layout, hi/lo interleaved ----
__global__ __launch_bounds__(256) void pack_w_kernel(
    const float* __restrict__ w, ushort* __restrict__ A, int CI, int CO)
{
    int i = blockIdx.x * 256 + threadIdx.x;
    if (i >= 27 * CI * CO * 2) return;
    int j = i & 7, hilo = (i >> 3) & 1, L = (i >> 4) & 63, rest = i >> 10;
    int NMT = CO >> 4, NCI = CI >> 5;
    int mt = rest % NMT; rest /= NMT;
    int ct = rest % NCI;
    int tap = rest / NCI;
    int co = mt * 16 + (L & 15);
    int ci = ct * 32 + (L >> 4) * 8 + j;
    float v = w[((size_t)co * CI + ci) * 27 + tap];
    ushort h = f2bf(v);
    A[i] = hilo ? f2bf(v - bf2f(h)) : h;
}

// ---------------- maxpool k3 s2 p1 (down_mask) ----------------
template<int DIN, int DOUT>
__global__ __launch_bounds__(256) void maxpool_kernel(
    const float* __restrict__ in, float* __restrict__ out)
{
    int i = blockIdx.x * 256 + threadIdx.x;
    constexpr int D3O = DOUT * DOUT * DOUT;
    if (i >= 2 * D3O) return;
    int b = i / D3O;
    int v = i - b * D3O;
    int z = v / (DOUT * DOUT), y = (v / DOUT) % DOUT, x = v % DOUT;
    float mx = 0.f;
    #pragma unroll
    for (int dz = 0; dz < 3; ++dz)
        #pragma unroll
        for (int dy = 0; dy < 3; ++dy)
            #pragma unroll
            for (int dx = 0; dx < 3; ++dx) {
                int zi = 2 * z - 1 + dz, yi = 2 * y - 1 + dy, xi = 2 * x - 1 + dx;
                if ((unsigned)zi < (unsigned)DIN && (unsigned)yi < (unsigned)DIN &&
                    (unsigned)xi < (unsigned)DIN)
                    mx = fmaxf(mx, in[(size_t)b * DIN * DIN * DIN + (zi * DIN + yi) * DIN + xi]);
            }
    out[i] = mx;
}

// ---------------- active-voxel list + dense index map ----------------
__global__ __launch_bounds__(256) void build_list_kernel(
    const float* __restrict__ m, int* __restrict__ list, int* __restrict__ idxmap,
    int* __restrict__ count)
{
    int i = blockIdx.x * 256 + threadIdx.x;
    if (i >= 2 * 262144) return;
    if (m[i] > 0.5f) {
        int k = atomicAdd(count, 1);
        if (k < ROWCAP) {
            list[k] = i;
            idxmap[i] = k;
        }
    }
}

// ---------------- stage1 conv-a (3->64, gathered) -> t1c[row][64] ----------------
__global__ __launch_bounds__(64) void stage1a_kernel(
    const float* __restrict__ x, const float* __restrict__ waT,
    const int* __restrict__ list, const int* __restrict__ count,
    float* __restrict__ t1c)
{
    __shared__ float smem[81];
    int n = min(*count, ROWCAP);
    for (int i = blockIdx.x; i < n; i += gridDim.x) {
        int lin = list[i];
        int b = lin >> 18;
        int v = lin & 262143;
        int z = v >> 12, y = (v >> 6) & 63, xx = v & 63;
        for (int j = threadIdx.x; j < 81; j += 64) {
            int ci = j / 27, t = j - ci * 27;
            int zz = z + t / 9 - 1, yy = y + (t / 3) % 3 - 1, xc = xx + t % 3 - 1;
            float val = 0.f;
            if ((unsigned)zz < 64u && (unsigned)yy < 64u && (unsigned)xc < 64u)
                val = x[(size_t)(b * 3 + ci) * 262144 + (zz << 12) + (yy << 6) + xc];
            smem[j] = val;
        }
        __syncthreads();
        float acc = 0.f;
        #pragma unroll 9
        for (int j = 0; j < 81; ++j)
            acc = fmaf(smem[j], waT[j * 64 + threadIdx.x], acc);
        t1c[(size_t)i * 64 + threadIdx.x] = leaky(acc);
        __syncthreads();
    }
}

// ---------------- stage1 conv-b (64->64, gathered) + 1x1 identity ----------------
__global__ __launch_bounds__(64) void stage1b_kernel(
    const float* __restrict__ t1c, const float* __restrict__ x,
    const float* __restrict__ wb4, const float* __restrict__ wdT,
    const int* __restrict__ list, const int* __restrict__ idxmap,
    const int* __restrict__ count,
    float* __restrict__ x1c)
{
    __shared__ float sw[4 * 1728];
    int n = min(*count, ROWCAP);
    int nq = (n + 3) >> 2;
    for (int q = blockIdx.x; q < nq; q += gridDim.x) {
        for (int vv = 0; vv < 4; ++vv) {
            int i = q * 4 + vv;
            int lin = (i < n) ? list[i] : list[0];
            int b = lin >> 18;
            int v = lin & 262143;
            int z = v >> 12, y = (v >> 6) & 63, xx = v & 63;
            const int* im = idxmap + b * 262144;
            #pragma unroll
            for (int t = 0; t < 27; ++t) {
                int zz = z + t / 9 - 1, yy = y + (t / 3) % 3 - 1, xc = xx + t % 3 - 1;
                float val = 0.f;
                if ((unsigned)zz < 64u && (unsigned)yy < 64u && (unsigned)xc < 64u) {
                    int r = im[(zz << 12) + (yy << 6) + xc];
                    if (r >= 0)
                        val = t1c[(size_t)r * 64 + threadIdx.x];
                }
                sw[vv * 1728 + threadIdx.x * 27 + t] = val;
            }
        }
        __syncthreads();
        float acc[4] = {0.f, 0.f, 0.f, 0.f};
        const float* wp = wb4 + threadIdx.x * 4;
        for (int j4 = 0; j4 < 432; ++j4) {
            float4 w = *(const float4*)(wp + (size_t)j4 * 256);
            #pragma unroll
            for (int vv = 0; vv < 4; ++vv) {
                float4 s = *(const float4*)(&sw[vv * 1728 + j4 * 4]);
                acc[vv] = fmaf(s.x, w.x, acc[vv]);
                acc[vv] = fmaf(s.y, w.y, acc[vv]);
                acc[vv] = fmaf(s.z, w.z, acc[vv]);
                acc[vv] = fmaf(s.w, w.w, acc[vv]);
            }
        }
        #pragma unroll
        for (int vv = 0; vv < 4; ++vv) {
            int i = q * 4 + vv;
            if (i < n) {
                int lin = list[i];
                int b = lin >> 18;
                int v = lin & 262143;
                float id = 0.f;
                #pragma unroll
                for (int ci = 0; ci < 3; ++ci)
                    id = fmaf(x[(size_t)(b * 3 + ci) * 262144 + v], wdT[ci * 64 + threadIdx.x], id);
                x1c[(size_t)i * 64 + threadIdx.x] = leaky(acc[vv] + id);
            }
        }
        __syncthreads();
    }
}

// ---------------- wd1 v2: lanes = channels, wave-uniform tap skip -------------
__global__ __launch_bounds__(128) void wd1_kernel(
    const float* __restrict__ x1c, const int* __restrict__ idxmap,
    const float* __restrict__ wT,   // [ci*27+tap][128]
    ushort* __restrict__ outp)
{
    __shared__ int   srr[27];
    __shared__ float sx[27][64];
    const int tid = threadIdx.x;
    const int v = blockIdx.x;           // 0..32767
    const int b = blockIdx.y;
    const int zo = v >> 10, yo = (v >> 5) & 31, xo = v & 31;
    const int* im = idxmap + b * 262144;

    if (tid < 27) {
        int kz = tid / 9, ky = (tid / 3) % 3, kx = tid % 3;
        int zi = 2 * zo - 1 + kz, yi = 2 * yo - 1 + ky, xi = 2 * xo - 1 + kx;
        int r = -1;
        if ((unsigned)zi < 64u && (unsigned)yi < 64u && (unsigned)xi < 64u)
            r = im[(zi << 12) + (yi << 6) + xi];
        srr[tid] = r;
    }
    __syncthreads();
    #pragma unroll 1
    for (int t = 0; t < 27; ++t) {
        int r = srr[t];
        if (r >= 0 && tid < 64)
            sx[t][tid] = x1c[(size_t)r * 64 + tid];
    }
    __syncthreads();

    float acc = 0.f;
    #pragma unroll 1
    for (int t = 0; t < 27; ++t) {
        if (srr[t] < 0) continue;
        const float* wp = wT + (size_t)t * 128 + tid;
        const float* xr = sx[t];
        #pragma unroll 8
        for (int ci = 0; ci < 64; ++ci)
            acc = fmaf(xr[ci], wp[(size_t)ci * 27 * 128], acc);
    }
    float val = leaky(acc);
    ushort hb = f2bf(val);
    ushort lb = f2bf(val - bf2f(hb));
    size_t vb = ((((size_t)b * 32 + zo) * 32 + yo) * 33 + xo) * 256 + 256;
    int off = choff(tid);
    outp[vb + off] = hb;
    outp[vb + off + 8] = lb;
}

// ---------------- MFMA implicit-GEMM conv v4 (product-major, interleaved) ----
template<int CI, int CO, int DI, int DO, int S, int RY, int NX, int NCT, int EPI>
__global__ __launch_bounds__(256) void mfma_conv3_kernel(
    const ushort* __restrict__ inp, const ushort* __restrict__ A,
    const float* __restrict__ mask, const ushort* __restrict__ resid,
    ushort* __restrict__ outp)
{
    constexpr int NCI = CI / 32;
    constexpr int NMT = CO / 16;
    constexpr int CV = CI * 2;
    constexpr int CVO = CO * 2;
    constexpr int YG = DO / RY;
    const int rg = blockIdx.x;
    const int y0 = (rg % YG) * RY;
    const int z = (rg / YG) % DO;
    const int b = rg / (YG * DO);
    const int wave = threadIdx.x >> 6;
    const int lane = threadIdx.x & 63;
    const int n_l = lane & 15;
    const int q = lane >> 4;
    const int mt0 = (blockIdx.y * 4 + wave) * NCT;

    f32x4 acc[NCT][RY][NX];
    #pragma unroll
    for (int a = 0; a < NCT; ++a)
        #pragma unroll
        for (int r = 0; r < RY; ++r)
            #pragma unroll
            for (int c = 0; c < NX; ++c)
                acc[a][r][c] = (f32x4){0.f, 0.f, 0.f, 0.f};

    const bf16x8 zero8 = {0, 0, 0, 0, 0, 0, 0, 0};

    for (int ct = 0; ct < NCI; ++ct) {
        #pragma unroll
        for (int dz = 0; dz < 3; ++dz) {
            int zp = z * S + dz - 1;
            if ((unsigned)zp >= (unsigned)DI) continue;
            #pragma unroll
            for (int dy = 0; dy < 3; ++dy) {
                size_t rowb[RY];
                bool vy[RY];
                #pragma unroll
                for (int ry = 0; ry < RY; ++ry) {
                    int yp = (y0 + ry) * S + dy - 1;
                    vy[ry] = (unsigned)yp < (unsigned)DI;
                    rowb[ry] = ((((size_t)b * DI + zp) * DI + (vy[ry] ? yp : 0)) * (DI + 1)) * CV + CV;
                }
                #pragma unroll
                for (int dx = 0; dx < 3; ++dx) {
                    const int tap = dz * 9 + dy * 3 + dx;
                    bf16x8 bh[RY][NX], bl[RY][NX];
                    #pragma unroll
                    for (int ry = 0; ry < RY; ++ry)
                        #pragma unroll
                        for (int nx = 0; nx < NX; ++nx) {
                            if (vy[ry]) {
                                int xp = (nx * 16 + n_l) * S + dx - 1;
                                size_t ba = rowb[ry] + (size_t)xp * CV + ct * 64 + q * 16;
                                bh[ry][nx] = *(const bf16x8*)(inp + ba);
                                bl[ry][nx] = *(const bf16x8*)(inp + ba + 8);
                            } else {
                                bh[ry][nx] = zero8;
                                bl[ry][nx] = zero8;
                            }
                        }
                    // hoist A-fragment loads for all mt tiles
                    bf16x8 ahf[NCT], alf[NCT];
                    #pragma unroll
                    for (int mt = 0; mt < NCT; ++mt) {
                        size_t aa = ((size_t)(tap * NCI + ct) * NMT + (mt0 + mt)) * 1024 + lane * 16;
                        ahf[mt] = *(const bf16x8*)(A + aa);
                        alf[mt] = *(const bf16x8*)(A + aa + 8);
                    }
                    // product-major issue: consecutive MFMAs hit different accs;
                    // per-acc order stays hh,hl,lh (bit-identical to r9)
                    #pragma unroll
                    for (int mt = 0; mt < NCT; ++mt)
                        #pragma unroll
                        for (int ry = 0; ry < RY; ++ry)
                            #pragma unroll
                            for (int nx = 0; nx < NX; ++nx)
                                acc[mt][ry][nx] = __builtin_amdgcn_mfma_f32_16x16x32_bf16(ahf[mt], bh[ry][nx], acc[mt][ry][nx], 0, 0, 0);
                    #pragma unroll
                    for (int mt = 0; mt < NCT; ++mt)
                        #pragma unroll
                        for (int ry = 0; ry < RY; ++ry)
                            #pragma unroll
                            for (int nx = 0; nx < NX; ++nx)
                                acc[mt][ry][nx] = __builtin_amdgcn_mfma_f32_16x16x32_bf16(ahf[mt], bl[ry][nx], acc[mt][ry][nx], 0, 0, 0);
                    #pragma unroll
                    for (int mt = 0; mt < NCT; ++mt)
                        #pragma unroll
                        for (int ry = 0; ry < RY; ++ry)
                            #pragma unroll
                            for (int nx = 0; nx < NX; ++nx)
                                acc[mt][ry][nx] = __builtin_amdgcn_mfma_f32_16x16x32_bf16(alf[mt], bh[ry][nx], acc[mt][ry][nx], 0, 0, 0);
                }
            }
        }
    }

    #pragma unroll
    for (int ry = 0; ry < RY; ++ry) {
        int yo = y0 + ry;
        #pragma unroll
        for (int nx = 0; nx < NX; ++nx) {
            int xo = nx * 16 + n_l;
            size_t vb = ((((size_t)b * DO + z) * DO + yo) * (DO + 1)) * CVO + CVO + (size_t)xo * CVO;
            float mval = 1.f;
            if (EPI & EPI_MASK) mval = mask[(((size_t)b * DO + z) * DO + yo) * DO + xo];
            #pragma unroll
            for (int mt = 0; mt < NCT; ++mt) {
                int c0 = (mt0 + mt) * 16 + q * 4;
                size_t oa = vb + choff(c0);
                float rs[4] = {0.f, 0.f, 0.f, 0.f};
                if (EPI & EPI_RESID) {
                    us4 rh4 = *(const us4*)(resid + oa);
                    us4 rl4 = *(const us4*)(resid + oa + 8);
                    #pragma unroll
                    for (int r = 0; r < 4; ++r) rs[r] = bf2f(rh4[r]) + bf2f(rl4[r]);
                }
                us4 oh, ol;
                #pragma unroll
                for (int r = 0; r < 4; ++r) {
                    float v = acc[mt][ry][nx][r];
                    if (EPI & EPI_MASK) v *= mval;
                    if (EPI & EPI_RESID) v += rs[r];
                    if (EPI & EPI_LEAKY) v = leaky(v);
                    ushort hb = f2bf(v);
                    oh[r] = hb;
                    ol[r] = f2bf(v - bf2f(hb));
                }
                *(us4*)(outp + oa) = oh;
                *(us4*)(outp + oa + 8) = ol;
            }
        }
    }
}

// ---------------- wd3 via MFMA (product-major) -> x4 fp32 ---------------------
__global__ __launch_bounds__(256) void wd3_mfma_kernel(
    const ushort* __restrict__ x3, const ushort* __restrict__ A,
    float* __restrict__ x4)
{
    constexpr int NCI = 8;   // 256/32
    constexpr int NMT = 8;   // 128/16
    const int blk = blockIdx.x;
    const int yg = blk & 3;
    const int z = (blk >> 2) & 7;
    const int b = blk >> 5;
    const int wave = threadIdx.x >> 6;
    const int lane = threadIdx.x & 63;
    const int n_l = lane & 15;
    const int q = lane >> 4;
    const int y = yg * 2 + (n_l >> 3);
    const int x = n_l & 7;
    const int mt0 = wave * 2;

    f32x4 acc[2];
    acc[0] = (f32x4){0.f, 0.f, 0.f, 0.f};
    acc[1] = (f32x4){0.f, 0.f, 0.f, 0.f};
    const bf16x8 zero8 = {0, 0, 0, 0, 0, 0, 0, 0};

    for (int ct = 0; ct < NCI; ++ct) {
        #pragma unroll
        for (int dz = 0; dz < 3; ++dz) {
            int zp = 2 * z + dz - 1;
            if ((unsigned)zp >= 16u) continue;
            #pragma unroll
            for (int dy = 0; dy < 3; ++dy) {
                int yp = 2 * y + dy - 1;
                bool vy = (unsigned)yp < 16u;
                int ypc = vy ? yp : 0;
                #pragma unroll
                for (int dx = 0; dx < 3; ++dx) {
                    int xp = 2 * x + dx - 1;
                    int tap = dz * 9 + dy * 3 + dx;
                    size_t ba = ((((size_t)b * 16 + zp) * 16 + ypc) * 17 + 1 + xp) * 512
                              + ct * 64 + q * 16;
                    bf16x8 bh = vy ? *(const bf16x8*)(x3 + ba) : zero8;
                    bf16x8 bl = vy ? *(const bf16x8*)(x3 + ba + 8) : zero8;
                    bf16x8 ahf[2], alf[2];
                    #pragma unroll
                    for (int mt = 0; mt < 2; ++mt) {
                        size_t aa = ((size_t)(tap * NCI + ct) * NMT + (mt0 + mt)) * 1024 + lane * 16;
                        ahf[mt] = *(const bf16x8*)(A + aa);
                        alf[mt] = *(const bf16x8*)(A + aa + 8);
                    }
                    #pragma unroll
                    for (int mt = 0; mt < 2; ++mt)
                        acc[mt] = __builtin_amdgcn_mfma_f32_16x16x32_bf16(ahf[mt], bh, acc[mt], 0, 0, 0);
                    #pragma unroll
                    for (int mt = 0; mt < 2; ++mt)
                        acc[mt] = __builtin_amdgcn_mfma_f32_16x16x32_bf16(ahf[mt], bl, acc[mt], 0, 0, 0);
                    #pragma unroll
                    for (int mt = 0; mt < 2; ++mt)
                        acc[mt] = __builtin_amdgcn_mfma_f32_16x16x32_bf16(alf[mt], bh, acc[mt], 0, 0, 0);
                }
            }
        }
    }
    #pragma unroll
    for (int mt = 0; mt < 2; ++mt)
        #pragma unroll
        for (int r = 0; r < 4; ++r) {
            int co = (mt0 + mt) * 16 + q * 4 + r;
            x4[((size_t)(b * 128 + co)) * 512 + z * 64 + y * 8 + x] = leaky(acc[mt][r]);
        }
}

// ---------------- final: mean/max pool over 8^3 -------------------------------
__global__ __launch_bounds__(64) void reduce_kernel(
    const float* __restrict__ x4, float* __restrict__ out)
{
    int bc = blockIdx.x;
    int b = bc >> 7, c = bc & 127;
    const float* p = x4 + (size_t)(b * 128 + c) * 512;
    float s = 0.f, mx = -3.4e38f;
    for (int i = threadIdx.x; i < 512; i += 64) {
        float v = p[i];
        s += v;
        mx = fmaxf(mx, v);
    }
    #pragma unroll
    for (int o = 32; o > 0; o >>= 1) {
        s += __shfl_down(s, o);
        mx = fmaxf(mx, __shfl_down(mx, o));
    }
    if (threadIdx.x == 0) {
        out[b * 256 + c] = s * (1.f / 512.f);
        out[b * 256 + 128 + c] = mx;
    }
}

__global__ __launch_bounds__(256) void zero_out_kernel(float* __restrict__ out, int n)
{
    int i = blockIdx.x * 256 + threadIdx.x;
    if (i < n) out[i] = 0.f;
}

// ---------------------------------------------------------------------------
extern "C" void kernel_launch(void* const* d_in, const int* in_sizes, int n_in,
                              void* d_out, int out_size, void* d_ws, size_t ws_size,
                              hipStream_t stream)
{
    (void)in_sizes; (void)n_in;
    const float* x    = (const float*)d_in[0];
    const float* mask = (const float*)d_in[1];
    const float* w1a  = (const float*)d_in[2];
    const float* w1b  = (const float*)d_in[3];
    const float* w1d  = (const float*)d_in[4];
    const float* wd1  = (const float*)d_in[5];
    const float* w2a  = (const float*)d_in[6];
    const float* w2b  = (const float*)d_in[7];
    const float* wd2  = (const float*)d_in[8];
    const float* w3a  = (const float*)d_in[9];
    const float* w3b  = (const float*)d_in[10];
    const float* wd3  = (const float*)d_in[11];
    float* out = (float*)d_out;
    char* ws = (char*)d_ws;

    const size_t RSZ = 34603520;      // stage-2 tensor region (interleaved)
    const size_t SZ3 = 8913920;       // stage-3 tensor bytes
    char* R1 = ws;
    char* R2 = ws + RSZ;
    char* R3 = ws + 2 * RSZ;
    size_t off = 3 * RSZ;
    auto alloc = [&](size_t bytes) { char* p = ws + off; off = (off + bytes + 255) & ~255ull; return p; };
    ushort* pk2a = (ushort*)alloc(1769472);
    ushort* pk2b = (ushort*)alloc(1769472);
    ushort* pkd2 = (ushort*)alloc(3538944);
    ushort* pk3a = (ushort*)alloc(7077888);
    ushort* pk3b = (ushort*)alloc(7077888);
    float*  wd1T = (float*)alloc(884736);
    float*  waT  = (float*)alloc(20736);
    float*  wb4  = (float*)alloc(442368);
    float*  wdTt = (float*)alloc(768);
    float*  m2   = (float*)alloc(262144);
    float*  m3   = (float*)alloc(32768);
    int*    cnt  = (int*)alloc(256);
    const size_t NEED = off;

    if (ws_size < NEED) {
        zero_out_kernel<<<dim3((out_size + 255) / 256), 256, 0, stream>>>(out, out_size);
        return;
    }

    // stage-1 scratch aliased into R2 (dead before t2 is written)
    float* t1c  = (float*)R2;
    float* x1c  = (float*)(R2 + 8388608);
    int*   idx  = (int*)(R2 + 16777216);
    int*   list = (int*)(R2 + 18874368);
    // late-phase aliases
    ushort* pkd3 = (ushort*)R1;       // xin3 dead after conv3b
    float*  x4   = (float*)R2;        // t3 dead after conv3b

    ushort* xin2 = (ushort*)R1;
    ushort* t2   = (ushort*)R2;
    ushort* x2   = (ushort*)R3;
    ushort* xin3 = (ushort*)R1;
    ushort* t3   = (ushort*)R2;
    ushort* x3   = (ushort*)R3;

    hipMemsetAsync(cnt, 0, 4, stream);
    hipMemsetAsync(idx, 0xFF, 2097152, stream);
    hipMemsetAsync(R1, 0, RSZ, stream);           // xin2 pads

    auto tg = [](int n) { return dim3((n + 255) / 256); };
    pack_w_kernel<<<tg(27 * 128 * 128 * 2), 256, 0, stream>>>(w2a, pk2a, 128, 128);
    pack_w_kernel<<<tg(27 * 128 * 128 * 2), 256, 0, stream>>>(w2b, pk2b, 128, 128);
    pack_w_kernel<<<tg(27 * 128 * 256 * 2), 256, 0, stream>>>(wd2, pkd2, 128, 256);
    pack_w_kernel<<<tg(27 * 256 * 256 * 2), 256, 0, stream>>>(w3a, pk3a, 256, 256);
    pack_w_kernel<<<tg(27 * 256 * 256 * 2), 256, 0, stream>>>(w3b, pk3b, 256, 256);
    transpose_w_kernel <<<tg(128 * 1728), 256, 0, stream>>>(wd1, wd1T, 128, 1728);
    transpose_w_kernel <<<tg(64 * 81),    256, 0, stream>>>(w1a, waT,  64, 81);
    transpose_w4_kernel<<<tg(64 * 1728),  256, 0, stream>>>(w1b, wb4,  64, 1728);
    transpose_w_kernel <<<tg(64 * 3),     256, 0, stream>>>(w1d, wdTt, 64, 3);

    maxpool_kernel<64, 32><<<dim3(2 * 32768 / 256), 256, 0, stream>>>(mask, m2);
    maxpool_kernel<32, 16><<<dim3(2 * 4096 / 256),  256, 0, stream>>>(m2, m3);
    build_list_kernel<<<dim3(2 * 262144 / 256), 256, 0, stream>>>(mask, list, idx, cnt);

    // stage 1 (sparse, fp32)
    stage1a_kernel<<<dim3(2048), 64, 0, stream>>>(x, waT, list, cnt, t1c);
    stage1b_kernel<<<dim3(2048), 64, 0, stream>>>(t1c, x, wb4, wdTt, list, idx, cnt, x1c);
    wd1_kernel<<<dim3(32768, 2), 128, 0, stream>>>(x1c, idx, wd1T, xin2);

    // stage-1 scratch dead; clear R2/R3 (t2/x2 pads)
    hipMemsetAsync(R2, 0, RSZ, stream);
    hipMemsetAsync(R3, 0, RSZ, stream);

    // stage2 res block (r9 grids: NCT=2, 1024 blocks)
    mfma_conv3_kernel<128, 128, 32, 32, 1, 2, 2, 2, EPI_MASK | EPI_LEAKY>
        <<<dim3(1024, 1), 256, 0, stream>>>(xin2, pk2a, m2, nullptr, t2);
    mfma_conv3_kernel<128, 128, 32, 32, 1, 2, 2, 2, EPI_MASK | EPI_RESID | EPI_LEAKY>
        <<<dim3(1024, 1), 256, 0, stream>>>(t2, pk2b, m2, xin2, x2);

    // xin2 dead -> clear xin3 area
    hipMemsetAsync(R1, 0, SZ3, stream);
    mfma_conv3_kernel<128, 256, 32, 16, 2, 2, 1, 2, EPI_LEAKY>
        <<<dim3(256, 2), 256, 0, stream>>>(x2, pkd2, nullptr, nullptr, xin3);

    hipMemsetAsync(R2, 0, SZ3, stream);
    mfma_conv3_kernel<256, 256, 16, 16, 1, 2, 1, 2, EPI_MASK | EPI_LEAKY>
        <<<dim3(256, 2), 256, 0, stream>>>(xin3, pk3a, m3, nullptr, t3);

    hipMemsetAsync(R3, 0, SZ3, stream);
    mfma_conv3_kernel<256, 256, 16, 16, 1, 2, 1, 2, EPI_MASK | EPI_RESID | EPI_LEAKY>
        <<<dim3(256, 2), 256, 0, stream>>>(t3, pk3b, m3, xin3, x3);

    // xin3 (R1) and t3 (R2) dead: pack wd3 -> R1, MFMA wd3 -> x4 (R2)
    pack_w_kernel<<<tg(27 * 256 * 128 * 2), 256, 0, stream>>>(wd3, pkd3, 256, 128);
    wd3_mfma_kernel<<<dim3(64), 256, 0, stream>>>(x3, pkd3, x4);

    reduce_kernel<<<dim3(256), 64, 0, stream>>>(x4, out);
}

// Round 12
// 2280.884 us; speedup vs baseline: 1.5755x; 1.0182x over previous
//
#include <hip/hip_runtime.h>

// ---------------------------------------------------------------------------
// SparseEncoderResUNet on MI355X — round 12: RY=4 stage-2 tiles.
// r11: product-major reorder neutral -> stall is exposed load latency per
// K-step. Fix: stage-2 convs use RY=4 (48 MFMAs per 20 loads per step, 2x
// longer burst per latency wait); grid 512 (2 blocks/CU). WPEU template knob
// caps VGPR via __launch_bounds__ 2nd arg (2 for stage-2, 4 elsewhere).
// wd2/conv3/wd3 unchanged (r9 shapes). Bit-identical math (absmax 0.0).
// ---------------------------------------------------------------------------

enum { EPI_MASK = 1, EPI_LEAKY = 2, EPI_RESID = 4 };
#define ROWCAP 32768

typedef short  bf16x8 __attribute__((ext_vector_type(8)));
typedef float  f32x4  __attribute__((ext_vector_type(4)));
typedef ushort us4    __attribute__((ext_vector_type(4)));

__device__ __forceinline__ float leaky(float v) { return v >= 0.f ? v : 0.2f * v; }
__device__ __forceinline__ ushort f2bf(float f) {
    unsigned u = __float_as_uint(f);
    return (ushort)((u + 0x7FFFu + ((u >> 16) & 1u)) >> 16);
}
__device__ __forceinline__ float bf2f(ushort h) {
    return __uint_as_float((unsigned)h << 16);
}
// channel c -> offset within a voxel's CI*2 block (interleaved hi/lo by 8)
__device__ __forceinline__ int choff(int c) {
    return (c >> 5) * 64 + ((c >> 3) & 3) * 16 + (c & 7);
}

// ---------------- weight transpose: w[co][cik] -> wT[cik][co] ----------------
__global__ __launch_bounds__(256) void transpose_w_kernel(
    const float* __restrict__ w, float* __restrict__ wT, int CO, int CIK)
{
    int i = blockIdx.x * 256 + threadIdx.x;
    if (i >= CO * CIK) return;
    int co = i / CIK, r = i - co * CIK;
    wT[(size_t)r * CO + co] = w[i];
}

// interleaved-by-4 layout for stage1b
__global__ __launch_bounds__(256) void transpose_w4_kernel(
    const float* __restrict__ w, float* __restrict__ w4, int CO, int CIK)
{
    int i = blockIdx.x * 256 + threadIdx.x;
    if (i >= CO * CIK) return;
    int co = i / CIK, r = i - co * CIK;
    w4[(((size_t)(r >> 2) * CO) + co) * 4 + (r & 3)] = w[i];
}

// ---------------- pack weights into MFMA A-frag layout, hi/lo interleaved ----
__global__ __launch_bounds__(256) void pack_w_kernel(
    const float* __restrict__ w, ushort* __restrict__ A, int CI, int CO)
{
    int i = blockIdx.x * 256 + threadIdx.x;
    if (i >= 27 * CI * CO * 2) return;
    int j = i & 7, hilo = (i >> 3) & 1, L = (i >> 4) & 63, rest = i >> 10;
    int NMT = CO >> 4, NCI = CI >> 5;
    int mt = rest % NMT; rest /= NMT;
    int ct = rest % NCI;
    int tap = rest / NCI;
    int co = mt * 16 + (L & 15);
    int ci = ct * 32 + (L >> 4) * 8 + j;
    float v = w[((size_t)co * CI + ci) * 27 + tap];
    ushort h = f2bf(v);
    A[i] = hilo ? f2bf(v - bf2f(h)) : h;
}

// ---------------- maxpool k3 s2 p1 (down_mask) ----------------
template<int DIN, int DOUT>
__global__ __launch_bounds__(256) void maxpool_kernel(
    const float* __restrict__ in, float* __restrict__ out)
{
    int i = blockIdx.x * 256 + threadIdx.x;
    constexpr int D3O = DOUT * DOUT * DOUT;
    if (i >= 2 * D3O) return;
    int b = i / D3O;
    int v = i - b * D3O;
    int z = v / (DOUT * DOUT), y = (v / DOUT) % DOUT, x = v % DOUT;
    float mx = 0.f;
    #pragma unroll
    for (int dz = 0; dz < 3; ++dz)
        #pragma unroll
        for (int dy = 0; dy < 3; ++dy)
            #pragma unroll
            for (int dx = 0; dx < 3; ++dx) {
                int zi = 2 * z - 1 + dz, yi = 2 * y - 1 + dy, xi = 2 * x - 1 + dx;
                if ((unsigned)zi < (unsigned)DIN && (unsigned)yi < (unsigned)DIN &&
                    (unsigned)xi < (unsigned)DIN)
                    mx = fmaxf(mx, in[(size_t)b * DIN * DIN * DIN + (zi * DIN + yi) * DIN + xi]);
            }
    out[i] = mx;
}

// ---------------- active-voxel list + dense index map ----------------
__global__ __launch_bounds__(256) void build_list_kernel(
    const float* __restrict__ m, int* __restrict__ list, int* __restrict__ idxmap,
    int* __restrict__ count)
{
    int i = blockIdx.x * 256 + threadIdx.x;
    if (i >= 2 * 262144) return;
    if (m[i] > 0.5f) {
        int k = atomicAdd(count, 1);
        if (k < ROWCAP) {
            list[k] = i;
            idxmap[i] = k;
        }
    }
}

// ---------------- stage1 conv-a (3->64, gathered) -> t1c[row][64] ----------------
__global__ __launch_bounds__(64) void stage1a_kernel(
    const float* __restrict__ x, const float* __restrict__ waT,
    const int* __restrict__ list, const int* __restrict__ count,
    float* __restrict__ t1c)
{
    __shared__ float smem[81];
    int n = min(*count, ROWCAP);
    for (int i = blockIdx.x; i < n; i += gridDim.x) {
        int lin = list[i];
        int b = lin >> 18;
        int v = lin & 262143;
        int z = v >> 12, y = (v >> 6) & 63, xx = v & 63;
        for (int j = threadIdx.x; j < 81; j += 64) {
            int ci = j / 27, t = j - ci * 27;
            int zz = z + t / 9 - 1, yy = y + (t / 3) % 3 - 1, xc = xx + t % 3 - 1;
            float val = 0.f;
            if ((unsigned)zz < 64u && (unsigned)yy < 64u && (unsigned)xc < 64u)
                val = x[(size_t)(b * 3 + ci) * 262144 + (zz << 12) + (yy << 6) + xc];
            smem[j] = val;
        }
        __syncthreads();
        float acc = 0.f;
        #pragma unroll 9
        for (int j = 0; j < 81; ++j)
            acc = fmaf(smem[j], waT[j * 64 + threadIdx.x], acc);
        t1c[(size_t)i * 64 + threadIdx.x] = leaky(acc);
        __syncthreads();
    }
}

// ---------------- stage1 conv-b (64->64, gathered) + 1x1 identity ----------------
__global__ __launch_bounds__(64) void stage1b_kernel(
    const float* __restrict__ t1c, const float* __restrict__ x,
    const float* __restrict__ wb4, const float* __restrict__ wdT,
    const int* __restrict__ list, const int* __restrict__ idxmap,
    const int* __restrict__ count,
    float* __restrict__ x1c)
{
    __shared__ float sw[4 * 1728];
    int n = min(*count, ROWCAP);
    int nq = (n + 3) >> 2;
    for (int q = blockIdx.x; q < nq; q += gridDim.x) {
        for (int vv = 0; vv < 4; ++vv) {
            int i = q * 4 + vv;
            int lin = (i < n) ? list[i] : list[0];
            int b = lin >> 18;
            int v = lin & 262143;
            int z = v >> 12, y = (v >> 6) & 63, xx = v & 63;
            const int* im = idxmap + b * 262144;
            #pragma unroll
            for (int t = 0; t < 27; ++t) {
                int zz = z + t / 9 - 1, yy = y + (t / 3) % 3 - 1, xc = xx + t % 3 - 1;
                float val = 0.f;
                if ((unsigned)zz < 64u && (unsigned)yy < 64u && (unsigned)xc < 64u) {
                    int r = im[(zz << 12) + (yy << 6) + xc];
                    if (r >= 0)
                        val = t1c[(size_t)r * 64 + threadIdx.x];
                }
                sw[vv * 1728 + threadIdx.x * 27 + t] = val;
            }
        }
        __syncthreads();
        float acc[4] = {0.f, 0.f, 0.f, 0.f};
        const float* wp = wb4 + threadIdx.x * 4;
        for (int j4 = 0; j4 < 432; ++j4) {
            float4 w = *(const float4*)(wp + (size_t)j4 * 256);
            #pragma unroll
            for (int vv = 0; vv < 4; ++vv) {
                float4 s = *(const float4*)(&sw[vv * 1728 + j4 * 4]);
                acc[vv] = fmaf(s.x, w.x, acc[vv]);
                acc[vv] = fmaf(s.y, w.y, acc[vv]);
                acc[vv] = fmaf(s.z, w.z, acc[vv]);
                acc[vv] = fmaf(s.w, w.w, acc[vv]);
            }
        }
        #pragma unroll
        for (int vv = 0; vv < 4; ++vv) {
            int i = q * 4 + vv;
            if (i < n) {
                int lin = list[i];
                int b = lin >> 18;
                int v = lin & 262143;
                float id = 0.f;
                #pragma unroll
                for (int ci = 0; ci < 3; ++ci)
                    id = fmaf(x[(size_t)(b * 3 + ci) * 262144 + v], wdT[ci * 64 + threadIdx.x], id);
                x1c[(size_t)i * 64 + threadIdx.x] = leaky(acc[vv] + id);
            }
        }
        __syncthreads();
    }
}

// ---------------- wd1 v2: lanes = channels, wave-uniform tap skip -------------
__global__ __launch_bounds__(128) void wd1_kernel(
    const float* __restrict__ x1c, const int* __restrict__ idxmap,
    const float* __restrict__ wT,   // [ci*27+tap][128]
    ushort* __restrict__ outp)
{
    __shared__ int   srr[27];
    __shared__ float sx[27][64];
    const int tid = threadIdx.x;
    const int v = blockIdx.x;           // 0..32767
    const int b = blockIdx.y;
    const int zo = v >> 10, yo = (v >> 5) & 31, xo = v & 31;
    const int* im = idxmap + b * 262144;

    if (tid < 27) {
        int kz = tid / 9, ky = (tid / 3) % 3, kx = tid % 3;
        int zi = 2 * zo - 1 + kz, yi = 2 * yo - 1 + ky, xi = 2 * xo - 1 + kx;
        int r = -1;
        if ((unsigned)zi < 64u && (unsigned)yi < 64u && (unsigned)xi < 64u)
            r = im[(zi << 12) + (yi << 6) + xi];
        srr[tid] = r;
    }
    __syncthreads();
    #pragma unroll 1
    for (int t = 0; t < 27; ++t) {
        int r = srr[t];
        if (r >= 0 && tid < 64)
            sx[t][tid] = x1c[(size_t)r * 64 + tid];
    }
    __syncthreads();

    float acc = 0.f;
    #pragma unroll 1
    for (int t = 0; t < 27; ++t) {
        if (srr[t] < 0) continue;
        const float* wp = wT + (size_t)t * 128 + tid;
        const float* xr = sx[t];
        #pragma unroll 8
        for (int ci = 0; ci < 64; ++ci)
            acc = fmaf(xr[ci], wp[(size_t)ci * 27 * 128], acc);
    }
    float val = leaky(acc);
    ushort hb = f2bf(val);
    ushort lb = f2bf(val - bf2f(hb));
    size_t vb = ((((size_t)b * 32 + zo) * 32 + yo) * 33 + xo) * 256 + 256;
    int off = choff(tid);
    outp[vb + off] = hb;
    outp[vb + off + 8] = lb;
}

// ---------------- MFMA implicit-GEMM conv v4 (product-major, interleaved) ----
// WPEU: __launch_bounds__ min-waves-per-EU (2 -> VGPR<=256 for big tiles).
template<int CI, int CO, int DI, int DO, int S, int RY, int NX, int NCT, int WPEU, int EPI>
__global__ __launch_bounds__(256, WPEU) void mfma_conv3_kernel(
    const ushort* __restrict__ inp, const ushort* __restrict__ A,
    const float* __restrict__ mask, const ushort* __restrict__ resid,
    ushort* __restrict__ outp)
{
    constexpr int NCI = CI / 32;
    constexpr int NMT = CO / 16;
    constexpr int CV = CI * 2;
    constexpr int CVO = CO * 2;
    constexpr int YG = DO / RY;
    const int rg = blockIdx.x;
    const int y0 = (rg % YG) * RY;
    const int z = (rg / YG) % DO;
    const int b = rg / (YG * DO);
    const int wave = threadIdx.x >> 6;
    const int lane = threadIdx.x & 63;
    const int n_l = lane & 15;
    const int q = lane >> 4;
    const int mt0 = (blockIdx.y * 4 + wave) * NCT;

    f32x4 acc[NCT][RY][NX];
    #pragma unroll
    for (int a = 0; a < NCT; ++a)
        #pragma unroll
        for (int r = 0; r < RY; ++r)
            #pragma unroll
            for (int c = 0; c < NX; ++c)
                acc[a][r][c] = (f32x4){0.f, 0.f, 0.f, 0.f};

    const bf16x8 zero8 = {0, 0, 0, 0, 0, 0, 0, 0};

    for (int ct = 0; ct < NCI; ++ct) {
        #pragma unroll
        for (int dz = 0; dz < 3; ++dz) {
            int zp = z * S + dz - 1;
            if ((unsigned)zp >= (unsigned)DI) continue;
            #pragma unroll
            for (int dy = 0; dy < 3; ++dy) {
                size_t rowb[RY];
                bool vy[RY];
                #pragma unroll
                for (int ry = 0; ry < RY; ++ry) {
                    int yp = (y0 + ry) * S + dy - 1;
                    vy[ry] = (unsigned)yp < (unsigned)DI;
                    rowb[ry] = ((((size_t)b * DI + zp) * DI + (vy[ry] ? yp : 0)) * (DI + 1)) * CV + CV;
                }
                #pragma unroll
                for (int dx = 0; dx < 3; ++dx) {
                    const int tap = dz * 9 + dy * 3 + dx;
                    bf16x8 bh[RY][NX], bl[RY][NX];
                    #pragma unroll
                    for (int ry = 0; ry < RY; ++ry)
                        #pragma unroll
                        for (int nx = 0; nx < NX; ++nx) {
                            if (vy[ry]) {
                                int xp = (nx * 16 + n_l) * S + dx - 1;
                                size_t ba = rowb[ry] + (size_t)xp * CV + ct * 64 + q * 16;
                                bh[ry][nx] = *(const bf16x8*)(inp + ba);
                                bl[ry][nx] = *(const bf16x8*)(inp + ba + 8);
                            } else {
                                bh[ry][nx] = zero8;
                                bl[ry][nx] = zero8;
                            }
                        }
                    bf16x8 ahf[NCT], alf[NCT];
                    #pragma unroll
                    for (int mt = 0; mt < NCT; ++mt) {
                        size_t aa = ((size_t)(tap * NCI + ct) * NMT + (mt0 + mt)) * 1024 + lane * 16;
                        ahf[mt] = *(const bf16x8*)(A + aa);
                        alf[mt] = *(const bf16x8*)(A + aa + 8);
                    }
                    // product-major: consecutive MFMAs hit different accs;
                    // per-acc order hh,hl,lh (bit-identical)
                    #pragma unroll
                    for (int mt = 0; mt < NCT; ++mt)
                        #pragma unroll
                        for (int ry = 0; ry < RY; ++ry)
                            #pragma unroll
                            for (int nx = 0; nx < NX; ++nx)
                                acc[mt][ry][nx] = __builtin_amdgcn_mfma_f32_16x16x32_bf16(ahf[mt], bh[ry][nx], acc[mt][ry][nx], 0, 0, 0);
                    #pragma unroll
                    for (int mt = 0; mt < NCT; ++mt)
                        #pragma unroll
                        for (int ry = 0; ry < RY; ++ry)
                            #pragma unroll
                            for (int nx = 0; nx < NX; ++nx)
                                acc[mt][ry][nx] = __builtin_amdgcn_mfma_f32_16x16x32_bf16(ahf[mt], bl[ry][nx], acc[mt][ry][nx], 0, 0, 0);
                    #pragma unroll
                    for (int mt = 0; mt < NCT; ++mt)
                        #pragma unroll
                        for (int ry = 0; ry < RY; ++ry)
                            #pragma unroll
                            for (int nx = 0; nx < NX; ++nx)
                                acc[mt][ry][nx] = __builtin_amdgcn_mfma_f32_16x16x32_bf16(alf[mt], bh[ry][nx], acc[mt][ry][nx], 0, 0, 0);
                }
            }
        }
    }

    #pragma unroll
    for (int ry = 0; ry < RY; ++ry) {
        int yo = y0 + ry;
        #pragma unroll
        for (int nx = 0; nx < NX; ++nx) {
            int xo = nx * 16 + n_l;
            size_t vb = ((((size_t)b * DO + z) * DO + yo) * (DO + 1)) * CVO + CVO + (size_t)xo * CVO;
            float mval = 1.f;
            if (EPI & EPI_MASK) mval = mask[(((size_t)b * DO + z) * DO + yo) * DO + xo];
            #pragma unroll
            for (int mt = 0; mt < NCT; ++mt) {
                int c0 = (mt0 + mt) * 16 + q * 4;
                size_t oa = vb + choff(c0);
                float rs[4] = {0.f, 0.f, 0.f, 0.f};
                if (EPI & EPI_RESID) {
                    us4 rh4 = *(const us4*)(resid + oa);
                    us4 rl4 = *(const us4*)(resid + oa + 8);
                    #pragma unroll
                    for (int r = 0; r < 4; ++r) rs[r] = bf2f(rh4[r]) + bf2f(rl4[r]);
                }
                us4 oh, ol;
                #pragma unroll
                for (int r = 0; r < 4; ++r) {
                    float v = acc[mt][ry][nx][r];
                    if (EPI & EPI_MASK) v *= mval;
                    if (EPI & EPI_RESID) v += rs[r];
                    if (EPI & EPI_LEAKY) v = leaky(v);
                    ushort hb = f2bf(v);
                    oh[r] = hb;
                    ol[r] = f2bf(v - bf2f(hb));
                }
                *(us4*)(outp + oa) = oh;
                *(us4*)(outp + oa + 8) = ol;
            }
        }
    }
}

// ---------------- wd3 via MFMA (product-major) -> x4 fp32 ---------------------
__global__ __launch_bounds__(256) void wd3_mfma_kernel(
    const ushort* __restrict__ x3, const ushort* __restrict__ A,
    float* __restrict__ x4)
{
    constexpr int NCI = 8;   // 256/32
    constexpr int NMT = 8;   // 128/16
    const int blk = blockIdx.x;
    const int yg = blk & 3;
    const int z = (blk >> 2) & 7;
    const int b = blk >> 5;
    const int wave = threadIdx.x >> 6;
    const int lane = threadIdx.x & 63;
    const int n_l = lane & 15;
    const int q = lane >> 4;
    const int y = yg * 2 + (n_l >> 3);
    const int x = n_l & 7;
    const int mt0 = wave * 2;

    f32x4 acc[2];
    acc[0] = (f32x4){0.f, 0.f, 0.f, 0.f};
    acc[1] = (f32x4){0.f, 0.f, 0.f, 0.f};
    const bf16x8 zero8 = {0, 0, 0, 0, 0, 0, 0, 0};

    for (int ct = 0; ct < NCI; ++ct) {
        #pragma unroll
        for (int dz = 0; dz < 3; ++dz) {
            int zp = 2 * z + dz - 1;
            if ((unsigned)zp >= 16u) continue;
            #pragma unroll
            for (int dy = 0; dy < 3; ++dy) {
                int yp = 2 * y + dy - 1;
                bool vy = (unsigned)yp < 16u;
                int ypc = vy ? yp : 0;
                #pragma unroll
                for (int dx = 0; dx < 3; ++dx) {
                    int xp = 2 * x + dx - 1;
                    int tap = dz * 9 + dy * 3 + dx;
                    size_t ba = ((((size_t)b * 16 + zp) * 16 + ypc) * 17 + 1 + xp) * 512
                              + ct * 64 + q * 16;
                    bf16x8 bh = vy ? *(const bf16x8*)(x3 + ba) : zero8;
                    bf16x8 bl = vy ? *(const bf16x8*)(x3 + ba + 8) : zero8;
                    bf16x8 ahf[2], alf[2];
                    #pragma unroll
                    for (int mt = 0; mt < 2; ++mt) {
                        size_t aa = ((size_t)(tap * NCI + ct) * NMT + (mt0 + mt)) * 1024 + lane * 16;
                        ahf[mt] = *(const bf16x8*)(A + aa);
                        alf[mt] = *(const bf16x8*)(A + aa + 8);
                    }
                    #pragma unroll
                    for (int mt = 0; mt < 2; ++mt)
                        acc[mt] = __builtin_amdgcn_mfma_f32_16x16x32_bf16(ahf[mt], bh, acc[mt], 0, 0, 0);
                    #pragma unroll
                    for (int mt = 0; mt < 2; ++mt)
                        acc[mt] = __builtin_amdgcn_mfma_f32_16x16x32_bf16(ahf[mt], bl, acc[mt], 0, 0, 0);
                    #pragma unroll
                    for (int mt = 0; mt < 2; ++mt)
                        acc[mt] = __builtin_amdgcn_mfma_f32_16x16x32_bf16(alf[mt], bh, acc[mt], 0, 0, 0);
                }
            }
        }
    }
    #pragma unroll
    for (int mt = 0; mt < 2; ++mt)
        #pragma unroll
        for (int r = 0; r < 4; ++r) {
            int co = (mt0 + mt) * 16 + q * 4 + r;
            x4[((size_t)(b * 128 + co)) * 512 + z * 64 + y * 8 + x] = leaky(acc[mt][r]);
        }
}

// ---------------- final: mean/max pool over 8^3 -------------------------------
__global__ __launch_bounds__(64) void reduce_kernel(
    const float* __restrict__ x4, float* __restrict__ out)
{
    int bc = blockIdx.x;
    int b = bc >> 7, c = bc & 127;
    const float* p = x4 + (size_t)(b * 128 + c) * 512;
    float s = 0.f, mx = -3.4e38f;
    for (int i = threadIdx.x; i < 512; i += 64) {
        float v = p[i];
        s += v;
        mx = fmaxf(mx, v);
    }
    #pragma unroll
    for (int o = 32; o > 0; o >>= 1) {
        s += __shfl_down(s, o);
        mx = fmaxf(mx, __shfl_down(mx, o));
    }
    if (threadIdx.x == 0) {
        out[b * 256 + c] = s * (1.f / 512.f);
        out[b * 256 + 128 + c] = mx;
    }
}

__global__ __launch_bounds__(256) void zero_out_kernel(float* __restrict__ out, int n)
{
    int i = blockIdx.x * 256 + threadIdx.x;
    if (i < n) out[i] = 0.f;
}

// ---------------------------------------------------------------------------
extern "C" void kernel_launch(void* const* d_in, const int* in_sizes, int n_in,
                              void* d_out, int out_size, void* d_ws, size_t ws_size,
                              hipStream_t stream)
{
    (void)in_sizes; (void)n_in;
    const float* x    = (const float*)d_in[0];
    const float* mask = (const float*)d_in[1];
    const float* w1a  = (const float*)d_in[2];
    const float* w1b  = (const float*)d_in[3];
    const float* w1d  = (const float*)d_in[4];
    const float* wd1  = (const float*)d_in[5];
    const float* w2a  = (const float*)d_in[6];
    const float* w2b  = (const float*)d_in[7];
    const float* wd2  = (const float*)d_in[8];
    const float* w3a  = (const float*)d_in[9];
    const float* w3b  = (const float*)d_in[10];
    const float* wd3  = (const float*)d_in[11];
    float* out = (float*)d_out;
    char* ws = (char*)d_ws;

    const size_t RSZ = 34603520;      // stage-2 tensor region (interleaved)
    const size_t SZ3 = 8913920;       // stage-3 tensor bytes
    char* R1 = ws;
    char* R2 = ws + RSZ;
    char* R3 = ws + 2 * RSZ;
    size_t off = 3 * RSZ;
    auto alloc = [&](size_t bytes) { char* p = ws + off; off = (off + bytes + 255) & ~255ull; return p; };
    ushort* pk2a = (ushort*)alloc(1769472);
    ushort* pk2b = (ushort*)alloc(1769472);
    ushort* pkd2 = (ushort*)alloc(3538944);
    ushort* pk3a = (ushort*)alloc(7077888);
    ushort* pk3b = (ushort*)alloc(7077888);
    float*  wd1T = (float*)alloc(884736);
    float*  waT  = (float*)alloc(20736);
    float*  wb4  = (float*)alloc(442368);
    float*  wdTt = (float*)alloc(768);
    float*  m2   = (float*)alloc(262144);
    float*  m3   = (float*)alloc(32768);
    int*    cnt  = (int*)alloc(256);
    const size_t NEED = off;

    if (ws_size < NEED) {
        zero_out_kernel<<<dim3((out_size + 255) / 256), 256, 0, stream>>>(out, out_size);
        return;
    }

    // stage-1 scratch aliased into R2 (dead before t2 is written)
    float* t1c  = (float*)R2;
    float* x1c  = (float*)(R2 + 8388608);
    int*   idx  = (int*)(R2 + 16777216);
    int*   list = (int*)(R2 + 18874368);
    // late-phase aliases
    ushort* pkd3 = (ushort*)R1;       // xin3 dead after conv3b
    float*  x4   = (float*)R2;        // t3 dead after conv3b

    ushort* xin2 = (ushort*)R1;
    ushort* t2   = (ushort*)R2;
    ushort* x2   = (ushort*)R3;
    ushort* xin3 = (ushort*)R1;
    ushort* t3   = (ushort*)R2;
    ushort* x3   = (ushort*)R3;

    hipMemsetAsync(cnt, 0, 4, stream);
    hipMemsetAsync(idx, 0xFF, 2097152, stream);
    hipMemsetAsync(R1, 0, RSZ, stream);           // xin2 pads

    auto tg = [](int n) { return dim3((n + 255) / 256); };
    pack_w_kernel<<<tg(27 * 128 * 128 * 2), 256, 0, stream>>>(w2a, pk2a, 128, 128);
    pack_w_kernel<<<tg(27 * 128 * 128 * 2), 256, 0, stream>>>(w2b, pk2b, 128, 128);
    pack_w_kernel<<<tg(27 * 128 * 256 * 2), 256, 0, stream>>>(wd2, pkd2, 128, 256);
    pack_w_kernel<<<tg(27 * 256 * 256 * 2), 256, 0, stream>>>(w3a, pk3a, 256, 256);
    pack_w_kernel<<<tg(27 * 256 * 256 * 2), 256, 0, stream>>>(w3b, pk3b, 256, 256);
    transpose_w_kernel <<<tg(128 * 1728), 256, 0, stream>>>(wd1, wd1T, 128, 1728);
    transpose_w_kernel <<<tg(64 * 81),    256, 0, stream>>>(w1a, waT,  64, 81);
    transpose_w4_kernel<<<tg(64 * 1728),  256, 0, stream>>>(w1b, wb4,  64, 1728);
    transpose_w_kernel <<<tg(64 * 3),     256, 0, stream>>>(w1d, wdTt, 64, 3);

    maxpool_kernel<64, 32><<<dim3(2 * 32768 / 256), 256, 0, stream>>>(mask, m2);
    maxpool_kernel<32, 16><<<dim3(2 * 4096 / 256),  256, 0, stream>>>(m2, m3);
    build_list_kernel<<<dim3(2 * 262144 / 256), 256, 0, stream>>>(mask, list, idx, cnt);

    // stage 1 (sparse, fp32)
    stage1a_kernel<<<dim3(2048), 64, 0, stream>>>(x, waT, list, cnt, t1c);
    stage1b_kernel<<<dim3(2048), 64, 0, stream>>>(t1c, x, wb4, wdTt, list, idx, cnt, x1c);
    wd1_kernel<<<dim3(32768, 2), 128, 0, stream>>>(x1c, idx, wd1T, xin2);

    // stage-1 scratch dead; clear R2/R3 (t2/x2 pads)
    hipMemsetAsync(R2, 0, RSZ, stream);
    hipMemsetAsync(R3, 0, RSZ, stream);

    // stage2 res block: RY=4 tiles, 512 blocks (2/CU), WPEU=2 (VGPR<=256)
    mfma_conv3_kernel<128, 128, 32, 32, 1, 4, 2, 2, 2, EPI_MASK | EPI_LEAKY>
        <<<dim3(512, 1), 256, 0, stream>>>(xin2, pk2a, m2, nullptr, t2);
    mfma_conv3_kernel<128, 128, 32, 32, 1, 4, 2, 2, 2, EPI_MASK | EPI_RESID | EPI_LEAKY>
        <<<dim3(512, 1), 256, 0, stream>>>(t2, pk2b, m2, xin2, x2);

    // xin2 dead -> clear xin3 area
    hipMemsetAsync(R1, 0, SZ3, stream);
    mfma_conv3_kernel<128, 256, 32, 16, 2, 2, 1, 2, 4, EPI_LEAKY>
        <<<dim3(256, 2), 256, 0, stream>>>(x2, pkd2, nullptr, nullptr, xin3);

    hipMemsetAsync(R2, 0, SZ3, stream);
    mfma_conv3_kernel<256, 256, 16, 16, 1, 2, 1, 2, 4, EPI_MASK | EPI_LEAKY>
        <<<dim3(256, 2), 256, 0, stream>>>(xin3, pk3a, m3, nullptr, t3);

    hipMemsetAsync(R3, 0, SZ3, stream);
    mfma_conv3_kernel<256, 256, 16, 16, 1, 2, 1, 2, 4, EPI_MASK | EPI_RESID | EPI_LEAKY>
        <<<dim3(256, 2), 256, 0, stream>>>(t3, pk3b, m3, xin3, x3);

    // xin3 (R1) and t3 (R2) dead: pack wd3 -> R1, MFMA wd3 -> x4 (R2)
    pack_w_kernel<<<tg(27 * 256 * 128 * 2), 256, 0, stream>>>(wd3, pkd3, 256, 128);
    wd3_mfma_kernel<<<dim3(64), 256, 0, stream>>>(x3, pkd3, x4);

    reduce_kernel<<<dim3(256), 64, 0, stream>>>(x4, out);
}